// Round 10
// baseline (233.723 us; speedup 1.0000x reference)
//
#include <hip/hip_runtime.h>
#include <stdint.h>

// GAT forward, MI355X. FP32 in/out; edge_index int32. N=50000, E=800000,
// HEADS=4, C=64 (HC=256).
// Pipeline (R18, 4 dispatches):
//   prep:  trans (blocks 0-31) + coarse hist per chunk -> cnt1[chunk][bucket].
//   mix:   blocks 0-255 = p1s (redundant-recompute base, LDS-cursor scatter
//          of packed recs); blocks 256+ = gemm. R18: 2-TERM GEMM — A staged
//          as a SINGLE RNE-bf16 plane, B split (trunc) in 2 planes:
//          acc = ah*bh + ah*bl. Dropped al*B term ~2^-9 rel — same order as
//          the bf16 H-store rounding that already dominates absmax (0.0156 =
//          8*2^-9), so absmax ~0.03 < 0.0575. MFMA -33%, ds_read -50%,
//          staging VALU halved, LDS 34KB at M=64 (R17 M=32 A/B: occupancy
//          was NOT the gemm limit, +1.4us only; B L2 traffic back to 200MB).
//   p2:    per-bucket fine hist + scan -> deg/offs/csr_src. LDS atomics only.
//   gather: R8 structure EXACTLY (69.2us proven best of 4 variants: R8 69.2 /
//          R10-dedup 75.3 / R12-hpsplit 71.7 / R16-headsplit 95.0. Lesson:
//          latency/VALU-co-bound; shuffles+extra waves+wider batches all lose
//          to plain 1-wave/node, 4ch/lane, 8-deep MLP, 36 VGPR). FROZEN.
// No grid barriers (R11 cg ~110us/sync, R14 spin ~25us/sync); no global
// atomics (R13: worth ~60us). Dispatch-fusion beyond this not worth it
// (R15: -3us for -3 dispatches). ~80us of dur_us is fixed harness floor
// (kernel-sum ~145 vs dur 228 across R13-R17).
// Softmax shift omitted: |e|<~12 -> exp<=1.6e5, fp32-safe; softmax is
// shift-invariant. Logit err now ~2^-9 rel (~0.1-0.2% weight shift) — still
// negligible vs 0.0575 threshold.

using u16 = unsigned short;
typedef float f32x4 __attribute__((ext_vector_type(4)));
typedef __bf16 bf16x8 __attribute__((ext_vector_type(8)));
typedef u16 u16x8 __attribute__((ext_vector_type(8)));

#define NEG 0.2f
#define APAD 264   // 256 + 8 u16 pad: row stride 528 B -> 2-way LDS aliasing (free)
#define NBLK1 256  // partition chunks (= p1s blocks)

__device__ __forceinline__ float bf2f(u16 u) {
    union { uint32_t i; float f; } v; v.i = ((uint32_t)u) << 16; return v.f;
}
__device__ __forceinline__ u16 f2bf(float f) {          // RNE
    union { float f; uint32_t i; } v; v.f = f;
    uint32_t r = v.i + 0x7FFFu + ((v.i >> 16) & 1u);
    return (u16)(r >> 16);
}
// trunc split: f ~= hi + lo with |err| ~ 2^-17 |f| (used for W only)
__device__ __forceinline__ void split2(float f, u16& h, u16& l) {
    union { float f; uint32_t i; } v; v.f = f;
    h = (u16)(v.i >> 16);
    float r = f - bf2f(h);
    union { float f; uint32_t i; } w; w.f = r;
    l = (u16)(w.i >> 16);
}
__device__ __forceinline__ float wexp(float e) {
    e = e >= 0.f ? e : NEG * e;
    return __expf(e);
}

// ---------------- prep: trans (blocks 0-31) + coarse hist (all blocks) -----
__global__ __launch_bounds__(256) void prep_kernel(
    const float* __restrict__ W, u16* __restrict__ Wfh, u16* __restrict__ Wfl,
    const int* __restrict__ edst, int* __restrict__ cnt1,
    int E, int Nn, int chunk)
{
    __shared__ int h1[256];
    const int tid = threadIdx.x, cb = blockIdx.x;
    h1[tid] = 0;
    __syncthreads();
    const int e0 = cb * chunk;
    const int e1 = (e0 + chunk < E) ? e0 + chunk : E;
    for (int e = e0 + tid; e < e1; e += 256) {
        int i = edst[e];
        i = ((unsigned)i < (unsigned)Nn) ? i : 0;
        atomicAdd(&h1[i >> 8], 1);                   // LDS atomic
    }
    __syncthreads();
    cnt1[cb * 256 + tid] = h1[tid];                  // chunk-major, coalesced

    if (cb < 32) {
        // Wf[((kg*16+nb)*64+l)*8+j] =
        //   split(W[(kg*32+(l>>4)*8+j)*256 + nb*16+(l&15)])
        const int f = cb * 4 + (tid >> 6);
        const int l = tid & 63;
        const int kg = f >> 4, nb = f & 15;
        const int n = nb * 16 + (l & 15);
        const int kb = kg * 32 + (l >> 4) * 8;
        u16x8 hv, lv;
#pragma unroll
        for (int j = 0; j < 8; j++) {
            u16 th, tl;
            split2(W[(size_t)(kb + j) * 256 + n], th, tl);
            hv[j] = th;
            lv[j] = tl;
        }
        *(u16x8*)(Wfh + ((size_t)f * 64 + l) * 8) = hv;
        *(u16x8*)(Wfl + ((size_t)f * 64 + l) * 8) = lv;
    }
}

// ---------------- mix: blocks 0-255 p1s scatter; blocks 256+ gemm (M=64) ---
__global__ __launch_bounds__(256) void mix_kernel(
    const float* __restrict__ X, const u16* __restrict__ Wfh,
    const u16* __restrict__ Wfl, const float* __restrict__ attS,
    const float* __restrict__ attD, u16* __restrict__ H,
    float* __restrict__ a_src, float* __restrict__ a_dst,
    const int* __restrict__ esrc, const int* __restrict__ edst,
    const int* __restrict__ cnt1, uint32_t* __restrict__ part,
    int E, int Nn, int chunk)
{
    __shared__ u16 Ah[64 * APAD];                    // single A plane (34KB)
    __shared__ int cur[256];
    __shared__ int wsum[4];
    const int tid = threadIdx.x;
    const int ln = tid & 63, wv = tid >> 6;

    if (blockIdx.x < NBLK1) {
        // ============== p1s: scatter chunk cb into bucket partitions =======
        const int cb = blockIdx.x;
        // rebuild base: thread tid owns bucket tid.
        int pre = 0, tot = 0;
        for (int c = 0; c < NBLK1; c++) {            // coalesced 1KB reads
            const int v = cnt1[c * 256 + tid];
            tot += v;
            pre += (c < cb) ? v : 0;
        }
        int s = tot;
#pragma unroll
        for (int o = 1; o < 64; o <<= 1) {
            int u = __shfl_up(s, o, 64);
            if (ln >= o) s += u;
        }
        if (ln == 63) wsum[wv] = s;
        __syncthreads();
        int wpre = 0;
#pragma unroll
        for (int w2 = 0; w2 < 4; w2++) wpre += (w2 < wv) ? wsum[w2] : 0;
        cur[tid] = (wpre + s - tot) + pre;           // bucket base + chunk pre
        __syncthreads();
        const int e0 = cb * chunk;
        const int e1 = (e0 + chunk < E) ? e0 + chunk : E;
        for (int e = e0 + tid; e < e1; e += 256) {
            int i = edst[e];
            i = ((unsigned)i < (unsigned)Nn) ? i : 0;
            int j = esrc[e];
            j = ((unsigned)j < (unsigned)Nn) ? j : 0;
            const int pos = atomicAdd(&cur[i >> 8], 1);    // LDS atomic
            part[pos] = (uint32_t)j | ((uint32_t)(i & 255) << 16); // N<65536
        }
        return;
    }

    // ================== gemm block (64 x 256 tile, 2-term) =================
    const int m0 = (blockIdx.x - NBLK1) * 64;
    const int wave = tid >> 6, lane = tid & 63;
    const int quad = lane >> 4, lr = lane & 15;

    // ---- stage X tile (64 rows x 256 cols) as single RNE bf16 plane ----
#pragma unroll
    for (int i = 0; i < 16; i++) {
        const int f = i * 256 + tid;            // float4 index in tile
        const int row = f >> 6;                 // 64 float4 per row
        const int c4 = (f & 63) * 4;
        int grow = m0 + row;
        if (grow >= Nn) grow = Nn - 1;          // clamp; stores guarded
        const float4 v = *(const float4*)(X + (size_t)grow * 256 + c4);
        uint2 hp;
        hp.x = (uint32_t)f2bf(v.x) | ((uint32_t)f2bf(v.y) << 16);
        hp.y = (uint32_t)f2bf(v.z) | ((uint32_t)f2bf(v.w) << 16);
        *(uint2*)(Ah + row * APAD + c4) = hp;   // 8B aligned
    }
    __syncthreads();

    f32x4 acc[4][4] = {};                       // [mi][ni]
    bf16x8 bh[2][4], bl[2][4];                  // B double buffer

    // prologue: kg=0 B frags (frag id = kg*16 + wave*4 + ni)
#pragma unroll
    for (int ni = 0; ni < 4; ni++) {
        const size_t o = ((size_t)(wave * 4 + ni) * 64 + lane) * 8;
        bh[0][ni] = *(const bf16x8*)(Wfh + o);
        bl[0][ni] = *(const bf16x8*)(Wfl + o);
    }

#pragma unroll
    for (int kg = 0; kg < 8; kg++) {
        const int st = kg & 1, ns = st ^ 1;
        if (kg < 7) {                           // prefetch kg+1 B
#pragma unroll
            for (int ni = 0; ni < 4; ni++) {
                const size_t o = ((size_t)((kg + 1) * 16 + wave * 4 + ni) * 64 + lane) * 8;
                bh[ns][ni] = *(const bf16x8*)(Wfh + o);
                bl[ns][ni] = *(const bf16x8*)(Wfl + o);
            }
        }
        bf16x8 ah[4];
#pragma unroll
        for (int mi = 0; mi < 4; mi++) {
            const int o = (mi * 16 + lr) * APAD + kg * 32 + quad * 8;
            ah[mi] = *(const bf16x8*)(Ah + o);  // ds_read_b128
        }
#pragma unroll
        for (int ni = 0; ni < 4; ni++)
#pragma unroll
            for (int mi = 0; mi < 4; mi++) {
                acc[mi][ni] = __builtin_amdgcn_mfma_f32_16x16x32_bf16(
                    ah[mi], bh[st][ni], acc[mi][ni], 0, 0, 0);
                acc[mi][ni] = __builtin_amdgcn_mfma_f32_16x16x32_bf16(
                    ah[mi], bl[st][ni], acc[mi][ni], 0, 0, 0);
            }
    }

    // ---- epilogue 1: att logits from fp32 acc (wave = head); reg/shfl only
    {
        float asv[4], adv[4];
#pragma unroll
        for (int ni = 0; ni < 4; ni++) {
            asv[ni] = attS[wave * 64 + ni * 16 + lr];
            adv[ni] = attD[wave * 64 + ni * 16 + lr];
        }
#pragma unroll
        for (int mi = 0; mi < 4; mi++)
#pragma unroll
            for (int r = 0; r < 4; r++) {
                float ps = 0.f, pd = 0.f;
#pragma unroll
                for (int ni = 0; ni < 4; ni++) {
                    ps += acc[mi][ni][r] * asv[ni];
                    pd += acc[mi][ni][r] * adv[ni];
                }
#pragma unroll
                for (int off = 8; off >= 1; off >>= 1) {
                    ps += __shfl_xor(ps, off, 16);   // reduce over lr group
                    pd += __shfl_xor(pd, off, 16);
                }
                if (lr == 0) {
                    const int row = m0 + mi * 16 + quad * 4 + r;
                    if (row < Nn) {
                        a_src[row * 4 + wave] = ps;
                        a_dst[row * 4 + wave] = pd;
                    }
                }
            }
    }

    // ---- epilogue 2: H store via LDS round-trip (coalesced dwordx4) ----
    __syncthreads();                            // main-loop Ah reads done
    const int n0 = wave * 64;
#pragma unroll
    for (int mi = 0; mi < 4; mi++)
#pragma unroll
        for (int ni = 0; ni < 4; ni++) {
            const int col = n0 + ni * 16 + lr;
#pragma unroll
            for (int r = 0; r < 4; r++)
                Ah[(mi * 16 + quad * 4 + r) * APAD + col] = f2bf(acc[mi][ni][r]);
        }
    __syncthreads();
#pragma unroll
    for (int swp = 0; swp < 8; swp++) {
        const int idx = swp * 256 + tid;        // 2048 chunks of 16B
        const int row = idx >> 5;               // 32 chunks per 512B row
        const int c16 = idx & 31;
        const int grow = m0 + row;
        if (grow < Nn)
            *(u16x8*)(H + (size_t)grow * 256 + c16 * 8) =
                *(const u16x8*)(Ah + row * APAD + c16 * 8);
    }
}

// ---------------- p2: per-bucket fine hist + scan -> deg/offs/csr_src ------
__global__ __launch_bounds__(256) void p2_kernel(
    const uint32_t* __restrict__ part, const int* __restrict__ cnt1,
    int* __restrict__ deg, int* __restrict__ offs, int* __restrict__ csr_src,
    int E, int Nn, int nb1)
{
    __shared__ int lds[256];
    __shared__ int wsum[4];
    __shared__ int sbd[2];
    const int b = blockIdx.x, tid = threadIdx.x;
    const int ln = tid & 63, wv = tid >> 6;

    // rebuild bucket bases: thread tid owns bucket tid
    int tot = 0;
    for (int c = 0; c < NBLK1; c++) tot += cnt1[c * 256 + tid];
    int s = tot;
#pragma unroll
    for (int o = 1; o < 64; o <<= 1) {
        int u = __shfl_up(s, o, 64);
        if (ln >= o) s += u;
    }
    if (ln == 63) wsum[wv] = s;
    __syncthreads();
    int wpre = 0;
#pragma unroll
    for (int w2 = 0; w2 < 4; w2++) wpre += (w2 < wv) ? wsum[w2] : 0;
    if (tid == b) { sbd[0] = wpre + s - tot; sbd[1] = wpre + s; }
    __syncthreads();
    const int bstart = sbd[0], bend = sbd[1];

    // fine hist (dst&255)
    lds[tid] = 0;
    __syncthreads();
    for (int e = bstart + tid; e < bend; e += 256)
        atomicAdd(&lds[part[e] >> 16], 1);           // LDS atomic
    __syncthreads();
    const int cnt = lds[tid];
    int s2 = cnt;
#pragma unroll
    for (int o = 1; o < 64; o <<= 1) {
        int u = __shfl_up(s2, o, 64);
        if (ln >= o) s2 += u;
    }
    if (ln == 63) wsum[wv] = s2;
    __syncthreads();
    int wpre2 = 0;
#pragma unroll
    for (int w2 = 0; w2 < 4; w2++) wpre2 += (w2 < wv) ? wsum[w2] : 0;
    const int ex = bstart + wpre2 + s2 - cnt;        // global exclusive
    const int node = (b << 8) + tid;
    if (node < Nn) { deg[node] = cnt; offs[node] = ex; }
    __syncthreads();
    lds[tid] = ex;                                   // reuse as cursors
    __syncthreads();
    for (int e = bstart + tid; e < bend; e += 256) {
        const uint32_t pr = part[e];
        const int pos = atomicAdd(&lds[pr >> 16], 1);       // LDS atomic
        csr_src[pos] = (int)(pr & 0xFFFFu);
    }
}

// ---------------- gather: 1 wave/node, 4 ch/thread, unroll x8 (R8 exact) ---
__global__ __launch_bounds__(256) void gather_kernel(
    const u16* __restrict__ H, const int* __restrict__ offs,
    const int* __restrict__ deg, const int* __restrict__ csr_src,
    const float* __restrict__ a_src, const float* __restrict__ a_dst,
    const float* __restrict__ bias, const float* __restrict__ prelu,
    float* __restrict__ out, int Nn)
{
    const int wave = threadIdx.x >> 6, lane = threadIdx.x & 63;
    const int node = blockIdx.x * 4 + wave;
    if (node >= Nn) return;
    const int head = lane >> 4;
    const int c = lane * 4;                          // 4 channels / thread

    const float adv = a_dst[node * 4 + head];
    float acc0, acc1, acc2, acc3, sumw;
    {   // self loop
        float ws = wexp(a_src[node * 4 + head] + adv);
        uint2 hv = *(const uint2*)(H + (size_t)node * 256 + c);
        acc0 = ws * bf2f((u16)hv.x);
        acc1 = ws * bf2f((u16)(hv.x >> 16));
        acc2 = ws * bf2f((u16)hv.y);
        acc3 = ws * bf2f((u16)(hv.y >> 16));
        sumw = ws;
    }
    const int start = offs[node];
    const int d = deg[node];
    int k = 0;
    for (; k + 8 <= d; k += 8) {                     // 8 H-rows in flight
        int j[8]; uint2 hv[8]; float w[8];
#pragma unroll
        for (int q = 0; q < 8; q++) j[q] = csr_src[start + k + q];
#pragma unroll
        for (int q = 0; q < 8; q++) hv[q] = *(const uint2*)(H + (size_t)j[q] * 256 + c);
#pragma unroll
        for (int q = 0; q < 8; q++) w[q] = wexp(a_src[j[q] * 4 + head] + adv);
#pragma unroll
        for (int q = 0; q < 8; q++) {
            acc0 += w[q] * bf2f((u16)hv[q].x);
            acc1 += w[q] * bf2f((u16)(hv[q].x >> 16));
            acc2 += w[q] * bf2f((u16)hv[q].y);
            acc3 += w[q] * bf2f((u16)(hv[q].y >> 16));
            sumw += w[q];
        }
    }
    for (; k + 4 <= d; k += 4) {
        int j[4]; uint2 hv[4]; float w[4];
#pragma unroll
        for (int q = 0; q < 4; q++) j[q] = csr_src[start + k + q];
#pragma unroll
        for (int q = 0; q < 4; q++) hv[q] = *(const uint2*)(H + (size_t)j[q] * 256 + c);
#pragma unroll
        for (int q = 0; q < 4; q++) w[q] = wexp(a_src[j[q] * 4 + head] + adv);
#pragma unroll
        for (int q = 0; q < 4; q++) {
            acc0 += w[q] * bf2f((u16)hv[q].x);
            acc1 += w[q] * bf2f((u16)(hv[q].x >> 16));
            acc2 += w[q] * bf2f((u16)hv[q].y);
            acc3 += w[q] * bf2f((u16)(hv[q].y >> 16));
            sumw += w[q];
        }
    }
    for (; k < d; k++) {
        const int j = csr_src[start + k];
        const uint2 hv = *(const uint2*)(H + (size_t)j * 256 + c);
        const float w = wexp(a_src[j * 4 + head] + adv);
        acc0 += w * bf2f((u16)hv.x);
        acc1 += w * bf2f((u16)(hv.x >> 16));
        acc2 += w * bf2f((u16)hv.y);
        acc3 += w * bf2f((u16)(hv.y >> 16));
        sumw += w;
    }
    const float inv = 1.f / (sumw + 1e-16f);
    const float pa = prelu[0];
    const float4 bv = *(const float4*)(bias + c);
    float4 ov;
    ov.x = acc0 * inv + bv.x; ov.x = ov.x >= 0.f ? ov.x : pa * ov.x;
    ov.y = acc1 * inv + bv.y; ov.y = ov.y >= 0.f ? ov.y : pa * ov.y;
    ov.z = acc2 * inv + bv.z; ov.z = ov.z >= 0.f ? ov.z : pa * ov.z;
    ov.w = acc3 * inv + bv.w; ov.w = ov.w >= 0.f ? ov.w : pa * ov.w;
    *(float4*)(out + (size_t)node * 256 + c) = ov;
}

// ---------------------------------------------------------------------------
extern "C" void kernel_launch(void* const* d_in, const int* in_sizes, int n_in,
                              void* d_out, int out_size, void* d_ws, size_t ws_size,
                              hipStream_t stream)
{
    const float* X    = (const float*)d_in[0];
    const int*   EI   = (const int*)d_in[1];
    const float* W    = (const float*)d_in[2];
    const float* attS = (const float*)d_in[3];
    const float* attD = (const float*)d_in[4];
    const float* bias = (const float*)d_in[5];
    const float* pa   = (const float*)d_in[6];

    const int Nn = in_sizes[0] / 256;   // 50000
    const int E  = in_sizes[1] / 2;     // 800000
    const int* esrc = EI;
    const int* edst = EI + E;

    const int nb1   = (Nn + 255) >> 8;              // 196 coarse buckets
    const int chunk = (E + NBLK1 - 1) / NBLK1;      // 3125

    // workspace carve (~34 MB), all segments 16B-aligned
    char* p = (char*)d_ws;
    u16*      H       = (u16*)p;      p += (size_t)Nn * 256 * 2;
    float*    a_src   = (float*)p;    p += (size_t)Nn * 4 * 4;
    float*    a_dst   = (float*)p;    p += (size_t)Nn * 4 * 4;
    u16*      Wfh     = (u16*)p;      p += 256 * 256 * 2;
    u16*      Wfl     = (u16*)p;      p += 256 * 256 * 2;
    int*      deg     = (int*)p;      p += (size_t)Nn * 4;
    int*      offs    = (int*)p;      p += (size_t)Nn * 4;
    int*      cnt1    = (int*)p;      p += (size_t)NBLK1 * 256 * 4;
    uint32_t* part    = (uint32_t*)p; p += (size_t)E * 4;
    int*      csr_src = (int*)p;      p += ((size_t)E + 16) * 4;

    prep_kernel<<<NBLK1, 256, 0, stream>>>(W, Wfh, Wfl, edst, cnt1,
                                           E, Nn, chunk);
    const int gemmBlocks = (Nn + 63) / 64;
    mix_kernel<<<NBLK1 + gemmBlocks, 256, 0, stream>>>(
        X, Wfh, Wfl, attS, attD, H, a_src, a_dst,
        esrc, edst, cnt1, part, E, Nn, chunk);
    p2_kernel<<<nb1, 256, 0, stream>>>(part, cnt1, deg, offs, csr_src,
                                       E, Nn, nb1);
    gather_kernel<<<(Nn + 3) / 4, 256, 0, stream>>>(H, offs, deg, csr_src,
                                                    a_src, a_dst, bias, pa,
                                                    (float*)d_out, Nn);
}

// Round 11
// 223.582 us; speedup vs baseline: 1.0454x; 1.0454x over previous
//
#include <hip/hip_runtime.h>
#include <stdint.h>

// GAT forward, MI355X. FP32 in/out; edge_index int32. N=50000, E=800000,
// HEADS=4, C=64 (HC=256).
// Pipeline (R19, 4 dispatches):
//   prep:  trans (blocks 0-31) + coarse hist per chunk -> cnt1[chunk][bucket].
//   mix:   blocks 0-255 = p1s (redundant-recompute base, LDS-cursor scatter
//          of packed recs); blocks 256+ = gemm. R19 = M=32 (R17-proven,
//          ~-5us: more blocks/CU, shorter staging, better balance behind
//          p1s) + 2-term single-A-plane (R18-proven absmax-safe: A staged
//          as one RNE bf16 plane, B trunc-split 2 planes, acc = ah*bh +
//          ah*bl; absmax stayed 0.015625 — GEMM RMS err << H-store
//          rounding). LDS/block 17KB -> ~8 blocks/CU.
//   p2:    per-bucket fine hist + scan -> deg/offs/csr_src. LDS atomics only.
//   gather: R8 structure EXACTLY, FROZEN (69.2us best of 4 variants:
//          R8 69.2 / R10-dedup 75.3 / R12-hpsplit 71.7 / R16-headsplit 95.0.
//          Latency/VALU-co-bound; shuffles+extra waves+wider batches lose).
// No grid barriers (R11 cg ~110us/sync, R14 spin ~25us/sync); no global
// atomics (R13: worth ~60us). Dispatch-fusion beyond this not worth it
// (R15: -3us for -3 dispatches). ~80us of dur_us is fixed harness floor
// (kernel-sum ~145 vs dur ~228 across R13-R18).
// Softmax shift omitted: |e|<~12 -> exp<=1.6e5, fp32-safe; softmax is
// shift-invariant. absmax 0.015625 vs 0.0575 threshold (verified R3-R18,
// incl. 2-term GEMM in R18).

using u16 = unsigned short;
typedef float f32x4 __attribute__((ext_vector_type(4)));
typedef __bf16 bf16x8 __attribute__((ext_vector_type(8)));
typedef u16 u16x8 __attribute__((ext_vector_type(8)));

#define NEG 0.2f
#define APAD 264   // 256 + 8 u16 pad: row stride 528 B -> 2-way LDS aliasing (free)
#define NBLK1 256  // partition chunks (= p1s blocks)

__device__ __forceinline__ float bf2f(u16 u) {
    union { uint32_t i; float f; } v; v.i = ((uint32_t)u) << 16; return v.f;
}
__device__ __forceinline__ u16 f2bf(float f) {          // RNE
    union { float f; uint32_t i; } v; v.f = f;
    uint32_t r = v.i + 0x7FFFu + ((v.i >> 16) & 1u);
    return (u16)(r >> 16);
}
// trunc split: f ~= hi + lo with |err| ~ 2^-17 |f| (used for W only)
__device__ __forceinline__ void split2(float f, u16& h, u16& l) {
    union { float f; uint32_t i; } v; v.f = f;
    h = (u16)(v.i >> 16);
    float r = f - bf2f(h);
    union { float f; uint32_t i; } w; w.f = r;
    l = (u16)(w.i >> 16);
}
__device__ __forceinline__ float wexp(float e) {
    e = e >= 0.f ? e : NEG * e;
    return __expf(e);
}

// ---------------- prep: trans (blocks 0-31) + coarse hist (all blocks) -----
__global__ __launch_bounds__(256) void prep_kernel(
    const float* __restrict__ W, u16* __restrict__ Wfh, u16* __restrict__ Wfl,
    const int* __restrict__ edst, int* __restrict__ cnt1,
    int E, int Nn, int chunk)
{
    __shared__ int h1[256];
    const int tid = threadIdx.x, cb = blockIdx.x;
    h1[tid] = 0;
    __syncthreads();
    const int e0 = cb * chunk;
    const int e1 = (e0 + chunk < E) ? e0 + chunk : E;
    for (int e = e0 + tid; e < e1; e += 256) {
        int i = edst[e];
        i = ((unsigned)i < (unsigned)Nn) ? i : 0;
        atomicAdd(&h1[i >> 8], 1);                   // LDS atomic
    }
    __syncthreads();
    cnt1[cb * 256 + tid] = h1[tid];                  // chunk-major, coalesced

    if (cb < 32) {
        // Wf[((kg*16+nb)*64+l)*8+j] =
        //   split(W[(kg*32+(l>>4)*8+j)*256 + nb*16+(l&15)])
        const int f = cb * 4 + (tid >> 6);
        const int l = tid & 63;
        const int kg = f >> 4, nb = f & 15;
        const int n = nb * 16 + (l & 15);
        const int kb = kg * 32 + (l >> 4) * 8;
        u16x8 hv, lv;
#pragma unroll
        for (int j = 0; j < 8; j++) {
            u16 th, tl;
            split2(W[(size_t)(kb + j) * 256 + n], th, tl);
            hv[j] = th;
            lv[j] = tl;
        }
        *(u16x8*)(Wfh + ((size_t)f * 64 + l) * 8) = hv;
        *(u16x8*)(Wfl + ((size_t)f * 64 + l) * 8) = lv;
    }
}

// ------- mix: blocks 0-255 p1s scatter; blocks 256+ gemm (M=32, 2-term) ----
__global__ __launch_bounds__(256) void mix_kernel(
    const float* __restrict__ X, const u16* __restrict__ Wfh,
    const u16* __restrict__ Wfl, const float* __restrict__ attS,
    const float* __restrict__ attD, u16* __restrict__ H,
    float* __restrict__ a_src, float* __restrict__ a_dst,
    const int* __restrict__ esrc, const int* __restrict__ edst,
    const int* __restrict__ cnt1, uint32_t* __restrict__ part,
    int E, int Nn, int chunk)
{
    __shared__ u16 Ah[32 * APAD];                    // single A plane (17KB)
    __shared__ int cur[256];
    __shared__ int wsum[4];
    const int tid = threadIdx.x;
    const int ln = tid & 63, wv = tid >> 6;

    if (blockIdx.x < NBLK1) {
        // ============== p1s: scatter chunk cb into bucket partitions =======
        const int cb = blockIdx.x;
        // rebuild base: thread tid owns bucket tid.
        int pre = 0, tot = 0;
        for (int c = 0; c < NBLK1; c++) {            // coalesced 1KB reads
            const int v = cnt1[c * 256 + tid];
            tot += v;
            pre += (c < cb) ? v : 0;
        }
        int s = tot;
#pragma unroll
        for (int o = 1; o < 64; o <<= 1) {
            int u = __shfl_up(s, o, 64);
            if (ln >= o) s += u;
        }
        if (ln == 63) wsum[wv] = s;
        __syncthreads();
        int wpre = 0;
#pragma unroll
        for (int w2 = 0; w2 < 4; w2++) wpre += (w2 < wv) ? wsum[w2] : 0;
        cur[tid] = (wpre + s - tot) + pre;           // bucket base + chunk pre
        __syncthreads();
        const int e0 = cb * chunk;
        const int e1 = (e0 + chunk < E) ? e0 + chunk : E;
        for (int e = e0 + tid; e < e1; e += 256) {
            int i = edst[e];
            i = ((unsigned)i < (unsigned)Nn) ? i : 0;
            int j = esrc[e];
            j = ((unsigned)j < (unsigned)Nn) ? j : 0;
            const int pos = atomicAdd(&cur[i >> 8], 1);    // LDS atomic
            part[pos] = (uint32_t)j | ((uint32_t)(i & 255) << 16); // N<65536
        }
        return;
    }

    // ================== gemm block (32 x 256 tile, 2-term) =================
    const int m0 = (blockIdx.x - NBLK1) * 32;
    const int wave = tid >> 6, lane = tid & 63;
    const int quad = lane >> 4, lr = lane & 15;

    // ---- stage X tile (32 rows x 256 cols) as single RNE bf16 plane ----
#pragma unroll
    for (int i = 0; i < 8; i++) {
        const int f = i * 256 + tid;            // float4 index in tile
        const int row = f >> 6;                 // 64 float4 per row
        const int c4 = (f & 63) * 4;
        int grow = m0 + row;
        if (grow >= Nn) grow = Nn - 1;          // clamp; stores guarded
        const float4 v = *(const float4*)(X + (size_t)grow * 256 + c4);
        uint2 hp;
        hp.x = (uint32_t)f2bf(v.x) | ((uint32_t)f2bf(v.y) << 16);
        hp.y = (uint32_t)f2bf(v.z) | ((uint32_t)f2bf(v.w) << 16);
        *(uint2*)(Ah + row * APAD + c4) = hp;   // 8B aligned
    }
    __syncthreads();

    f32x4 acc[2][4] = {};                       // [mi][ni]
    bf16x8 bh[2][4], bl[2][4];                  // B double buffer

    // prologue: kg=0 B frags (frag id = kg*16 + wave*4 + ni)
#pragma unroll
    for (int ni = 0; ni < 4; ni++) {
        const size_t o = ((size_t)(wave * 4 + ni) * 64 + lane) * 8;
        bh[0][ni] = *(const bf16x8*)(Wfh + o);
        bl[0][ni] = *(const bf16x8*)(Wfl + o);
    }

#pragma unroll
    for (int kg = 0; kg < 8; kg++) {
        const int st = kg & 1, ns = st ^ 1;
        if (kg < 7) {                           // prefetch kg+1 B
#pragma unroll
            for (int ni = 0; ni < 4; ni++) {
                const size_t o = ((size_t)((kg + 1) * 16 + wave * 4 + ni) * 64 + lane) * 8;
                bh[ns][ni] = *(const bf16x8*)(Wfh + o);
                bl[ns][ni] = *(const bf16x8*)(Wfl + o);
            }
        }
        bf16x8 ah[2];
#pragma unroll
        for (int mi = 0; mi < 2; mi++) {
            const int o = (mi * 16 + lr) * APAD + kg * 32 + quad * 8;
            ah[mi] = *(const bf16x8*)(Ah + o);  // ds_read_b128
        }
#pragma unroll
        for (int ni = 0; ni < 4; ni++)
#pragma unroll
            for (int mi = 0; mi < 2; mi++) {
                acc[mi][ni] = __builtin_amdgcn_mfma_f32_16x16x32_bf16(
                    ah[mi], bh[st][ni], acc[mi][ni], 0, 0, 0);
                acc[mi][ni] = __builtin_amdgcn_mfma_f32_16x16x32_bf16(
                    ah[mi], bl[st][ni], acc[mi][ni], 0, 0, 0);
            }
    }

    // ---- epilogue 1: att logits from fp32 acc (wave = head); reg/shfl only
    {
        float asv[4], adv[4];
#pragma unroll
        for (int ni = 0; ni < 4; ni++) {
            asv[ni] = attS[wave * 64 + ni * 16 + lr];
            adv[ni] = attD[wave * 64 + ni * 16 + lr];
        }
#pragma unroll
        for (int mi = 0; mi < 2; mi++)
#pragma unroll
            for (int r = 0; r < 4; r++) {
                float ps = 0.f, pd = 0.f;
#pragma unroll
                for (int ni = 0; ni < 4; ni++) {
                    ps += acc[mi][ni][r] * asv[ni];
                    pd += acc[mi][ni][r] * adv[ni];
                }
#pragma unroll
                for (int off = 8; off >= 1; off >>= 1) {
                    ps += __shfl_xor(ps, off, 16);   // reduce over lr group
                    pd += __shfl_xor(pd, off, 16);
                }
                if (lr == 0) {
                    const int row = m0 + mi * 16 + quad * 4 + r;
                    if (row < Nn) {
                        a_src[row * 4 + wave] = ps;
                        a_dst[row * 4 + wave] = pd;
                    }
                }
            }
    }

    // ---- epilogue 2: H store via LDS round-trip (coalesced dwordx4) ----
    __syncthreads();                            // main-loop Ah reads done
    const int n0 = wave * 64;
#pragma unroll
    for (int mi = 0; mi < 2; mi++)
#pragma unroll
        for (int ni = 0; ni < 4; ni++) {
            const int col = n0 + ni * 16 + lr;
#pragma unroll
            for (int r = 0; r < 4; r++)
                Ah[(mi * 16 + quad * 4 + r) * APAD + col] = f2bf(acc[mi][ni][r]);
        }
    __syncthreads();
#pragma unroll
    for (int swp = 0; swp < 4; swp++) {
        const int idx = swp * 256 + tid;        // 1024 chunks of 16B
        const int row = idx >> 5;               // 32 chunks per 512B row
        const int c16 = idx & 31;
        const int grow = m0 + row;
        if (grow < Nn)
            *(u16x8*)(H + (size_t)grow * 256 + c16 * 8) =
                *(const u16x8*)(Ah + row * APAD + c16 * 8);
    }
}

// ---------------- p2: per-bucket fine hist + scan -> deg/offs/csr_src ------
__global__ __launch_bounds__(256) void p2_kernel(
    const uint32_t* __restrict__ part, const int* __restrict__ cnt1,
    int* __restrict__ deg, int* __restrict__ offs, int* __restrict__ csr_src,
    int E, int Nn, int nb1)
{
    __shared__ int lds[256];
    __shared__ int wsum[4];
    __shared__ int sbd[2];
    const int b = blockIdx.x, tid = threadIdx.x;
    const int ln = tid & 63, wv = tid >> 6;

    // rebuild bucket bases: thread tid owns bucket tid
    int tot = 0;
    for (int c = 0; c < NBLK1; c++) tot += cnt1[c * 256 + tid];
    int s = tot;
#pragma unroll
    for (int o = 1; o < 64; o <<= 1) {
        int u = __shfl_up(s, o, 64);
        if (ln >= o) s += u;
    }
    if (ln == 63) wsum[wv] = s;
    __syncthreads();
    int wpre = 0;
#pragma unroll
    for (int w2 = 0; w2 < 4; w2++) wpre += (w2 < wv) ? wsum[w2] : 0;
    if (tid == b) { sbd[0] = wpre + s - tot; sbd[1] = wpre + s; }
    __syncthreads();
    const int bstart = sbd[0], bend = sbd[1];

    // fine hist (dst&255)
    lds[tid] = 0;
    __syncthreads();
    for (int e = bstart + tid; e < bend; e += 256)
        atomicAdd(&lds[part[e] >> 16], 1);           // LDS atomic
    __syncthreads();
    const int cnt = lds[tid];
    int s2 = cnt;
#pragma unroll
    for (int o = 1; o < 64; o <<= 1) {
        int u = __shfl_up(s2, o, 64);
        if (ln >= o) s2 += u;
    }
    if (ln == 63) wsum[wv] = s2;
    __syncthreads();
    int wpre2 = 0;
#pragma unroll
    for (int w2 = 0; w2 < 4; w2++) wpre2 += (w2 < wv) ? wsum[w2] : 0;
    const int ex = bstart + wpre2 + s2 - cnt;        // global exclusive
    const int node = (b << 8) + tid;
    if (node < Nn) { deg[node] = cnt; offs[node] = ex; }
    __syncthreads();
    lds[tid] = ex;                                   // reuse as cursors
    __syncthreads();
    for (int e = bstart + tid; e < bend; e += 256) {
        const uint32_t pr = part[e];
        const int pos = atomicAdd(&lds[pr >> 16], 1);       // LDS atomic
        csr_src[pos] = (int)(pr & 0xFFFFu);
    }
}

// ---------------- gather: 1 wave/node, 4 ch/thread, unroll x8 (R8 exact) ---
__global__ __launch_bounds__(256) void gather_kernel(
    const u16* __restrict__ H, const int* __restrict__ offs,
    const int* __restrict__ deg, const int* __restrict__ csr_src,
    const float* __restrict__ a_src, const float* __restrict__ a_dst,
    const float* __restrict__ bias, const float* __restrict__ prelu,
    float* __restrict__ out, int Nn)
{
    const int wave = threadIdx.x >> 6, lane = threadIdx.x & 63;
    const int node = blockIdx.x * 4 + wave;
    if (node >= Nn) return;
    const int head = lane >> 4;
    const int c = lane * 4;                          // 4 channels / thread

    const float adv = a_dst[node * 4 + head];
    float acc0, acc1, acc2, acc3, sumw;
    {   // self loop
        float ws = wexp(a_src[node * 4 + head] + adv);
        uint2 hv = *(const uint2*)(H + (size_t)node * 256 + c);
        acc0 = ws * bf2f((u16)hv.x);
        acc1 = ws * bf2f((u16)(hv.x >> 16));
        acc2 = ws * bf2f((u16)hv.y);
        acc3 = ws * bf2f((u16)(hv.y >> 16));
        sumw = ws;
    }
    const int start = offs[node];
    const int d = deg[node];
    int k = 0;
    for (; k + 8 <= d; k += 8) {                     // 8 H-rows in flight
        int j[8]; uint2 hv[8]; float w[8];
#pragma unroll
        for (int q = 0; q < 8; q++) j[q] = csr_src[start + k + q];
#pragma unroll
        for (int q = 0; q < 8; q++) hv[q] = *(const uint2*)(H + (size_t)j[q] * 256 + c);
#pragma unroll
        for (int q = 0; q < 8; q++) w[q] = wexp(a_src[j[q] * 4 + head] + adv);
#pragma unroll
        for (int q = 0; q < 8; q++) {
            acc0 += w[q] * bf2f((u16)hv[q].x);
            acc1 += w[q] * bf2f((u16)(hv[q].x >> 16));
            acc2 += w[q] * bf2f((u16)hv[q].y);
            acc3 += w[q] * bf2f((u16)(hv[q].y >> 16));
            sumw += w[q];
        }
    }
    for (; k + 4 <= d; k += 4) {
        int j[4]; uint2 hv[4]; float w[4];
#pragma unroll
        for (int q = 0; q < 4; q++) j[q] = csr_src[start + k + q];
#pragma unroll
        for (int q = 0; q < 4; q++) hv[q] = *(const uint2*)(H + (size_t)j[q] * 256 + c);
#pragma unroll
        for (int q = 0; q < 4; q++) w[q] = wexp(a_src[j[q] * 4 + head] + adv);
#pragma unroll
        for (int q = 0; q < 4; q++) {
            acc0 += w[q] * bf2f((u16)hv[q].x);
            acc1 += w[q] * bf2f((u16)(hv[q].x >> 16));
            acc2 += w[q] * bf2f((u16)hv[q].y);
            acc3 += w[q] * bf2f((u16)(hv[q].y >> 16));
            sumw += w[q];
        }
    }
    for (; k < d; k++) {
        const int j = csr_src[start + k];
        const uint2 hv = *(const uint2*)(H + (size_t)j * 256 + c);
        const float w = wexp(a_src[j * 4 + head] + adv);
        acc0 += w * bf2f((u16)hv.x);
        acc1 += w * bf2f((u16)(hv.x >> 16));
        acc2 += w * bf2f((u16)hv.y);
        acc3 += w * bf2f((u16)(hv.y >> 16));
        sumw += w;
    }
    const float inv = 1.f / (sumw + 1e-16f);
    const float pa = prelu[0];
    const float4 bv = *(const float4*)(bias + c);
    float4 ov;
    ov.x = acc0 * inv + bv.x; ov.x = ov.x >= 0.f ? ov.x : pa * ov.x;
    ov.y = acc1 * inv + bv.y; ov.y = ov.y >= 0.f ? ov.y : pa * ov.y;
    ov.z = acc2 * inv + bv.z; ov.z = ov.z >= 0.f ? ov.z : pa * ov.z;
    ov.w = acc3 * inv + bv.w; ov.w = ov.w >= 0.f ? ov.w : pa * ov.w;
    *(float4*)(out + (size_t)node * 256 + c) = ov;
}

// ---------------------------------------------------------------------------
extern "C" void kernel_launch(void* const* d_in, const int* in_sizes, int n_in,
                              void* d_out, int out_size, void* d_ws, size_t ws_size,
                              hipStream_t stream)
{
    const float* X    = (const float*)d_in[0];
    const int*   EI   = (const int*)d_in[1];
    const float* W    = (const float*)d_in[2];
    const float* attS = (const float*)d_in[3];
    const float* attD = (const float*)d_in[4];
    const float* bias = (const float*)d_in[5];
    const float* pa   = (const float*)d_in[6];

    const int Nn = in_sizes[0] / 256;   // 50000
    const int E  = in_sizes[1] / 2;     // 800000
    const int* esrc = EI;
    const int* edst = EI + E;

    const int nb1   = (Nn + 255) >> 8;              // 196 coarse buckets
    const int chunk = (E + NBLK1 - 1) / NBLK1;      // 3125

    // workspace carve (~34 MB), all segments 16B-aligned
    char* p = (char*)d_ws;
    u16*      H       = (u16*)p;      p += (size_t)Nn * 256 * 2;
    float*    a_src   = (float*)p;    p += (size_t)Nn * 4 * 4;
    float*    a_dst   = (float*)p;    p += (size_t)Nn * 4 * 4;
    u16*      Wfh     = (u16*)p;      p += 256 * 256 * 2;
    u16*      Wfl     = (u16*)p;      p += 256 * 256 * 2;
    int*      deg     = (int*)p;      p += (size_t)Nn * 4;
    int*      offs    = (int*)p;      p += (size_t)Nn * 4;
    int*      cnt1    = (int*)p;      p += (size_t)NBLK1 * 256 * 4;
    uint32_t* part    = (uint32_t*)p; p += (size_t)E * 4;
    int*      csr_src = (int*)p;      p += ((size_t)E + 16) * 4;

    prep_kernel<<<NBLK1, 256, 0, stream>>>(W, Wfh, Wfl, edst, cnt1,
                                           E, Nn, chunk);
    const int gemmBlocks = (Nn + 31) / 32;
    mix_kernel<<<NBLK1 + gemmBlocks, 256, 0, stream>>>(
        X, Wfh, Wfl, attS, attD, H, a_src, a_dst,
        esrc, edst, cnt1, part, E, Nn, chunk);
    p2_kernel<<<nb1, 256, 0, stream>>>(part, cnt1, deg, offs, csr_src,
                                       E, Nn, nb1);
    gather_kernel<<<(Nn + 3) / 4, 256, 0, stream>>>(H, offs, deg, csr_src,
                                                    a_src, a_dst, bias, pa,
                                                    (float*)d_out, Nn);
}